// Round 1
// 305.842 us; speedup vs baseline: 1.1196x; 1.1196x over previous
//
#include <hip/hip_runtime.h>

#define H 224
#define W 224
#define HW (H*W)
#define BATCH 2
#define CIN 64
#define COUT 64
#define NOFF 18
#define K576 576          // K = 64 ch * 9 taps
#define OFFS 20           // off LDS stride (18 live, f4-aligned)
#define NBLK (BATCH*HW/64)          // 1568 tiles (8x8 pixels)
#define NB8  (NBLK/8)               // 196 blocks per XCD span
#define TC8  28                     // 224/8 tiles per image row/col
#define XROW 68                     // staged patch ch-stride (64 + 4 pad)
#define PRW 10                      // patch rows (8 + 2 halo)
#define PCW 10                      // patch cols
#define LDROW 72                    // epilogue staging stride

typedef __attribute__((ext_vector_type(8))) short bf16x8;
typedef __attribute__((ext_vector_type(4))) short s16x4;
typedef __attribute__((ext_vector_type(4))) float f32x4;

__device__ inline short f2bf(float f) {
    unsigned u = __float_as_uint(f);
    u += 0x7FFF + ((u >> 16) & 1);
    return (short)(u >> 16);
}
__device__ inline float bf2f(short h) {
    return __uint_as_float(((unsigned)(unsigned short)h) << 16);
}
__device__ inline void split_bf(float x, short& hi, short& lo) {
    hi = f2bf(x);
    lo = f2bf(x - bf2f(hi));
}
__device__ inline void split_bf4(float a, float b, float c, float d,
                                 s16x4& h4, s16x4& l4) {
    short h0, l0, h1, l1, h2, l2, h3, l3;
    split_bf(a, h0, l0); split_bf(b, h1, l1);
    split_bf(c, h2, l2); split_bf(d, h3, l3);
    h4 = (s16x4){h0, h1, h2, h3};
    l4 = (s16x4){l0, l1, l2, l3};
}
__device__ inline void split_bf8(float a0, float a1, float a2, float a3,
                                 float a4, float a5, float a6, float a7,
                                 bf16x8& hi, bf16x8& lo) {
    s16x4 h0, l0, h1, l1;
    split_bf4(a0, a1, a2, a3, h0, l0);
    split_bf4(a4, a5, a6, a7, h1, l1);
    hi = __builtin_shufflevector(h0, h1, 0, 1, 2, 3, 4, 5, 6, 7);
    lo = __builtin_shufflevector(l0, l1, 0, 1, 2, 3, 4, 5, 6, 7);
}
__device__ inline int swizzle_blk(int raw) {
    return (raw & 7) * NB8 + (raw >> 3);
}
__device__ __forceinline__ float f4get(float4 v, int k) {
    switch (k & 3) { case 0: return v.x; case 1: return v.y; case 2: return v.z; default: return v.w; }
}

// ---------------------------------------------------------------------------
// Weight prep -> WAVE-CONTIGUOUS fragment layout (unchanged):
// Deform:  Wd[((chunk*9+kt)*4+nt)*512 + lane*8 + e]
//   n = nt*16 + (lane&15); c = chunk*32 + (lane>>4)*8 + e; tap = kt
// Offconv: Wo[((chunk*9+kt)*2+ntb)*512 + lane*8 + e]   (n>=18 rows zero)
// ---------------------------------------------------------------------------
__global__ __launch_bounds__(256) void k_prepw(const float* __restrict__ wconv,
                                               const float* __restrict__ woff,
                                               short* __restrict__ Wtdh,
                                               short* __restrict__ Wtdl,
                                               short* __restrict__ Wtoh,
                                               short* __restrict__ Wtol) {
    int t = blockIdx.x * 256 + threadIdx.x;
    if (t < COUT * K576) {
        int e = t & 7, lane = (t >> 3) & 63, rest = t >> 9;
        int nt = rest & 3, kt9 = rest >> 2;
        int kt = kt9 % 9, chunk = kt9 / 9;
        int n = nt * 16 + (lane & 15);
        int c = chunk * 32 + (lane >> 4) * 8 + e;
        short h, l; split_bf(wconv[n * K576 + c * 9 + kt], h, l);
        Wtdh[t] = h; Wtdl[t] = l;
    }
    int t2 = t - COUT * K576;
    if (t2 >= 0 && t2 < 32 * K576) {
        int e = t2 & 7, lane = (t2 >> 3) & 63, rest = t2 >> 9;
        int ntb = rest & 1, kt9 = rest >> 1;
        int kt = kt9 % 9, chunk = kt9 / 9;
        int n = ntb * 16 + (lane & 15);
        int c = chunk * 32 + (lane >> 4) * 8 + e;
        float v = (n < NOFF) ? woff[n * K576 + c * 9 + kt] : 0.0f;
        short h, l; split_bf(v, h, l);
        Wtoh[t2] = h; Wtol[t2] = l;
    }
}

// ---------------------------------------------------------------------------
// x NCHW -> NHWC.
// ---------------------------------------------------------------------------
__global__ __launch_bounds__(256) void k_transpose(const float* __restrict__ x,
                                                   float* __restrict__ xT) {
    __shared__ float Lt[64][65];
    int blk = blockIdx.x, t = threadIdx.x;
    int px0 = blk * 64;
    int b   = px0 / HW;
    int ij0 = px0 - b * HW;
    int lane = t & 63, g = t >> 6;
#pragma unroll
    for (int r = 0; r < 16; ++r) {
        int c = r * 4 + g;
        Lt[c][lane] = x[(b * CIN + c) * HW + ij0 + lane];
    }
    __syncthreads();
#pragma unroll
    for (int r = 0; r < 16; ++r) {
        int px = r * 4 + g;
        xT[((size_t)(b * HW + ij0 + px)) * 64 + lane] = Lt[lane][px];
    }
}

// ---------------------------------------------------------------------------
// FUSED, wave-autonomous. Block = 8x8 pixels, 4 waves, each wave owns 16
// pixels (2 rows) and ALL 64 outputs for them. MFMA A-fragments (16x16x32:
// row=lane&15, k=(lane>>4)*8+e) are produced IN REGISTERS by the consuming
// lane itself: lane (l15,quad) interpolates pixel l15, channels quad*8..+7.
// -> no A-tile LDS staging, no K-loop barriers (5 barriers/block vs 13).
// LDS 32320 B (10x10x64 patch + 5KB offset xpose) -> 4-5 blocks/CU.
// ---------------------------------------------------------------------------
template <bool OUT_NHWC>
__global__ __launch_bounds__(256, 4) void k_fused(const float* __restrict__ xT,
                                                  const short* __restrict__ Wtoh,
                                                  const short* __restrict__ Wtol,
                                                  const float* __restrict__ boff,
                                                  const short* __restrict__ Wtdh,
                                                  const short* __restrict__ Wtdl,
                                                  float* __restrict__ out,
                                                  float* __restrict__ part) {
    // LDS: Xs 27200 | offL 5120 = 32320 B. Ld (18432) + Sr (2048) reuse them.
    __shared__ __align__(16) char smem[PRW * PCW * XROW * 4 + 64 * OFFS * 4];
    float* Xs   = (float*)smem;
    float* offL = (float*)(smem + PRW * PCW * XROW * 4);

    const int t    = threadIdx.x;
    const int lane = t & 63;
    const int wv   = t >> 6;
    const int l15  = lane & 15;
    const int quad = lane >> 4;
    const int vb   = swizzle_blk(blockIdx.x);
    const int b    = vb / (TC8 * TC8);
    const int rem  = vb - b * (TC8 * TC8);
    const int i0   = (rem / TC8) * 8;
    const int j0   = (rem % TC8) * 8;
    const int lp   = wv * 16 + l15;          // this lane's pixel 0..63
    const int i    = i0 + (lp >> 3);
    const int j    = j0 + (lp & 7);

    const float* xb = xT + (size_t)(b * HW) * 64;

    // ---- stage 10x10x64ch patch (border-clamped), shared by both phases ----
#pragma unroll
    for (int k = 0; k < 7; ++k) {
        int idx = k * 256 + t;               // 1600 = 100 slots x 16 f4
        if (idx < PRW * PCW * 16) {
            int slot = idx >> 4, e = idx & 15;
            int sr = slot / PCW, sc = slot - sr * PCW;
            int rr = min(max(i0 - 1 + sr, 0), H - 1);
            int cc = min(max(j0 - 1 + sc, 0), W - 1);
            *(float4*)&Xs[slot * XROW + e * 4] =
                *(const float4*)(xb + (size_t)(rr * W + cc) * 64 + e * 4);
        }
    }
    __syncthreads();

    // ============ PHASE 1: offset conv (zero-pad via mask), per-wave ============
    f32x4 aoc0 = (f32x4){0.f, 0.f, 0.f, 0.f};
    f32x4 aoc1 = (f32x4){0.f, 0.f, 0.f, 0.f};
#pragma unroll
    for (int kt = 0; kt < 9; ++kt) {
        const int di = kt / 3, dj = kt % 3;
        const int ii = i + di - 1, jj = j + dj - 1;
        const bool ok = (ii >= 0) && (ii < H) && (jj >= 0) && (jj < W);
        const float* xp = &Xs[(((lp >> 3) + di) * PCW + (lp & 7) + dj) * XROW + quad * 8];
#pragma unroll
        for (int chunk = 0; chunk < 2; ++chunk) {
            float4 va = make_float4(0.f, 0.f, 0.f, 0.f), vb4 = va;
            if (ok) {
                va  = *(const float4*)(xp + chunk * 32);
                vb4 = *(const float4*)(xp + chunk * 32 + 4);
            }
            bf16x8 afh, afl;
            split_bf8(va.x, va.y, va.z, va.w, vb4.x, vb4.y, vb4.z, vb4.w, afh, afl);
            const int fb = (chunk * 9 + kt) * 2 * 512 + lane * 8;
            bf16x8 bh0 = *(const bf16x8*)(Wtoh + fb);
            bf16x8 bl0 = *(const bf16x8*)(Wtol + fb);
            aoc0 = __builtin_amdgcn_mfma_f32_16x16x32_bf16(afh, bh0, aoc0, 0, 0, 0);
            aoc0 = __builtin_amdgcn_mfma_f32_16x16x32_bf16(afl, bh0, aoc0, 0, 0, 0);
            aoc0 = __builtin_amdgcn_mfma_f32_16x16x32_bf16(afh, bl0, aoc0, 0, 0, 0);
            bf16x8 bh1 = *(const bf16x8*)(Wtoh + fb + 512);
            bf16x8 bl1 = *(const bf16x8*)(Wtol + fb + 512);
            aoc1 = __builtin_amdgcn_mfma_f32_16x16x32_bf16(afh, bh1, aoc1, 0, 0, 0);
            aoc1 = __builtin_amdgcn_mfma_f32_16x16x32_bf16(afl, bh1, aoc1, 0, 0, 0);
            aoc1 = __builtin_amdgcn_mfma_f32_16x16x32_bf16(afh, bl1, aoc1, 0, 0, 0);
        }
    }
    // redistribute offsets: C layout holds [px=quad*4+r][n=l15(+16)] -> offL
    {
        const int pr0 = wv * 16 + quad * 4;
        const float bi = boff[l15];
#pragma unroll
        for (int r = 0; r < 4; ++r)
            offL[(pr0 + r) * OFFS + l15] = aoc0[r] + bi;
        if (l15 < 2) {
            const float bi2 = boff[16 + l15];
#pragma unroll
            for (int r = 0; r < 4; ++r)
                offL[(pr0 + r) * OFFS + 16 + l15] = aoc1[r] + bi2;
        }
    }
    __syncthreads();

    // ============ PHASE 2: deformable sampling + conv, per-wave ============
    const float* ofp = &offL[(wv * 16 + l15) * OFFS];
    const float4 ofA = *(const float4*)(ofp + 0);
    const float4 ofB = *(const float4*)(ofp + 4);
    const float4 ofC = *(const float4*)(ofp + 8);
    const float4 ofD = *(const float4*)(ofp + 12);
    const float4 ofE = *(const float4*)(ofp + 16);
#define OFFSEL(idx) ((idx) < 4 ? f4get(ofA, (idx)) : (idx) < 8 ? f4get(ofB, (idx)-4) : \
                     (idx) < 12 ? f4get(ofC, (idx)-8) : (idx) < 16 ? f4get(ofD, (idx)-12) : f4get(ofE, (idx)-16))

    f32x4 acc[4];
    acc[0] = (f32x4){0.f, 0.f, 0.f, 0.f};
    acc[1] = acc[0]; acc[2] = acc[0]; acc[3] = acc[0];

#pragma unroll
    for (int kt = 0; kt < 9; ++kt) {
        float px_f = (float)(i + kt / 3) + OFFSEL(kt);
        float py_f = (float)(j + kt % 3) + OFFSEL(9 + kt);
        float qx = floorf(px_f), qy = floorf(py_f);
        int ltx = min(max((int)qx, 0), H - 1);
        int lty = min(max((int)qy, 0), W - 1);
        int rbx = min(max((int)qx + 1, 0), H - 1);
        int rby = min(max((int)qy + 1, 0), W - 1);
        float cpx = fminf(fmaxf(px_f, 0.0f), (float)(H - 1));
        float cpy = fminf(fmaxf(py_f, 0.0f), (float)(W - 1));
        float alt = 1.0f + ((float)ltx - cpx);
        float arb = 1.0f - ((float)rbx - cpx);
        float blt = 1.0f + ((float)lty - cpy);
        float brb = 1.0f - ((float)rby - cpy);
        float g0 = alt * blt, g1 = arb * brb, g2 = alt * brb, g3 = arb * blt;
        int slr = ltx - (i0 - 1), srr = rbx - (i0 - 1);
        int slc = lty - (j0 - 1), src = rby - (j0 - 1);
        const bool inp = ((unsigned)slr < (unsigned)PRW) & ((unsigned)srr < (unsigned)PRW) &
                         ((unsigned)slc < (unsigned)PCW) & ((unsigned)src < (unsigned)PCW);
#pragma unroll
        for (int chunk = 0; chunk < 2; ++chunk) {
            const int ch = chunk * 32 + quad * 8;
            float s[8];
#pragma unroll
            for (int hf = 0; hf < 2; ++hf) {
                const int cho = ch + hf * 4;
                float4 v0, v1, v2, v3;
                if (inp) {
                    v0 = *(const float4*)&Xs[(slr * PCW + slc) * XROW + cho];
                    v1 = *(const float4*)&Xs[(srr * PCW + src) * XROW + cho];
                    v2 = *(const float4*)&Xs[(slr * PCW + src) * XROW + cho];
                    v3 = *(const float4*)&Xs[(srr * PCW + slc) * XROW + cho];
                } else {
                    v0 = *(const float4*)(xb + (size_t)(ltx * W + lty) * 64 + cho);
                    v1 = *(const float4*)(xb + (size_t)(rbx * W + rby) * 64 + cho);
                    v2 = *(const float4*)(xb + (size_t)(ltx * W + rby) * 64 + cho);
                    v3 = *(const float4*)(xb + (size_t)(rbx * W + lty) * 64 + cho);
                }
                s[hf * 4 + 0] = g0 * v0.x + g1 * v1.x + g2 * v2.x + g3 * v3.x;
                s[hf * 4 + 1] = g0 * v0.y + g1 * v1.y + g2 * v2.y + g3 * v3.y;
                s[hf * 4 + 2] = g0 * v0.z + g1 * v1.z + g2 * v2.z + g3 * v3.z;
                s[hf * 4 + 3] = g0 * v0.w + g1 * v1.w + g2 * v2.w + g3 * v3.w;
            }
            bf16x8 afh, afl;
            split_bf8(s[0], s[1], s[2], s[3], s[4], s[5], s[6], s[7], afh, afl);
#pragma unroll
            for (int nt = 0; nt < 4; ++nt) {
                const int fb = ((chunk * 9 + kt) * 4 + nt) * 512 + lane * 8;
                bf16x8 bfh = *(const bf16x8*)(Wtdh + fb);
                bf16x8 bfl = *(const bf16x8*)(Wtdl + fb);
                acc[nt] = __builtin_amdgcn_mfma_f32_16x16x32_bf16(afh, bfh, acc[nt], 0, 0, 0);
                acc[nt] = __builtin_amdgcn_mfma_f32_16x16x32_bf16(afl, bfh, acc[nt], 0, 0, 0);
                acc[nt] = __builtin_amdgcn_mfma_f32_16x16x32_bf16(afh, bfl, acc[nt], 0, 0, 0);
            }
        }
    }
#undef OFFSEL

    // ============ EPILOGUE: store + fused stats (Ld reuses Xs) ============
    __syncthreads();                          // all Xs reads done before overwrite
    float* Ld = Xs;
    const int pr0 = wv * 16 + quad * 4;
    if (OUT_NHWC) {
#pragma unroll
        for (int nt = 0; nt < 4; ++nt) {
            int c = nt * 16 + l15;
#pragma unroll
            for (int r = 0; r < 4; ++r)
                Ld[(pr0 + r) * LDROW + c] = acc[nt][r];
        }
        __syncthreads();
#pragma unroll
        for (int it = 0; it < 4; ++it) {      // 1024 f4 = 64px x 16 groups
            int idx = it * 256 + t;
            int px = idx >> 4, c4 = idx & 15;
            float4 v = *(float4*)&Ld[px * LDROW + c4 * 4];
            int pij = (i0 + (px >> 3)) * W + j0 + (px & 7);
            *(float4*)(out + (size_t)(b * HW + pij) * 64 + c4 * 4) = v;
        }
    } else {
#pragma unroll
        for (int nt = 0; nt < 4; ++nt) {
            int c = nt * 16 + l15;
#pragma unroll
            for (int r = 0; r < 4; ++r)
                Ld[c * LDROW + pr0 + r] = acc[nt][r];
        }
        __syncthreads();
#pragma unroll
        for (int it = 0; it < 4; ++it) {      // 1024 f4 = 64ch x 16 groups
            int idx = it * 256 + t;
            int c = idx >> 4, p4 = idx & 15;
            float4 v = *(float4*)&Ld[c * LDROW + p4 * 4];
            int pij = (i0 + (p4 >> 1)) * W + j0 + (p4 & 1) * 4;
            *(float4*)(out + (size_t)(b * COUT + c) * HW + pij) = v;
        }
    }
    {
        float* Sr = offL;                     // offsets dead; 2KB needed
        int c = t & 63, g = t >> 6;
        float s = 0.f, q = 0.f;
        if (OUT_NHWC) {
#pragma unroll
            for (int k = 0; k < 16; ++k) {
                float v = Ld[(g * 16 + k) * LDROW + c];
                s += v; q += v * v;
            }
        } else {
#pragma unroll
            for (int k4 = 0; k4 < 4; ++k4) {
                float4 v = *(const float4*)&Ld[c * LDROW + g * 16 + k4 * 4];
                s += v.x + v.y + v.z + v.w;
                q += v.x * v.x + v.y * v.y + v.z * v.z + v.w * v.w;
            }
        }
        Sr[g * 64 + c]       = s;
        Sr[256 + g * 64 + c] = q;
        __syncthreads();
        if (t < 64) {
            float ts = Sr[t] + Sr[64 + t] + Sr[128 + t] + Sr[192 + t];
            float tq = Sr[256 + t] + Sr[320 + t] + Sr[384 + t] + Sr[448 + t];
            part[(size_t)blockIdx.x * 128 + t]      = ts;
            part[(size_t)blockIdx.x * 128 + 64 + t] = tq;
        }
    }
}

// ---------------------------------------------------------------------------
// Reduce per-block partials -> per-channel scale/shift. grid = 64.
// ---------------------------------------------------------------------------
__global__ __launch_bounds__(256) void k_stats2(const float* __restrict__ part,
                                                const float* __restrict__ gamma,
                                                const float* __restrict__ beta,
                                                float* __restrict__ ss) {
    int c = blockIdx.x, t = threadIdx.x;
    float s = 0.f, q = 0.f;
    for (int k = t; k < NBLK; k += 256) {
        s += part[(size_t)k * 128 + c];
        q += part[(size_t)k * 128 + 64 + c];
    }
#pragma unroll
    for (int d = 32; d > 0; d >>= 1) {
        s += __shfl_down(s, d, 64);
        q += __shfl_down(q, d, 64);
    }
    __shared__ float red[8];
    int wv = t >> 6;
    if ((t & 63) == 0) { red[wv] = s; red[4 + wv] = q; }
    __syncthreads();
    if (t == 0) {
        float ts = red[0] + red[1] + red[2] + red[3];
        float tq = red[4] + red[5] + red[6] + red[7];
        const float inv_m = 1.0f / (float)(BATCH * HW);
        float mu    = ts * inv_m;
        float var   = tq * inv_m - mu * mu;
        float scale = rsqrtf(var + 1e-5f) * gamma[c];
        ss[c]      = scale;
        ss[64 + c] = beta[c] - mu * scale;
    }
}

// ---------------------------------------------------------------------------
// BN+ReLU on NHWC (stage 1).
// ---------------------------------------------------------------------------
__global__ __launch_bounds__(256) void k_bnrelu_nhwc(const float* __restrict__ y,
                                                     const float* __restrict__ ss,
                                                     float* __restrict__ out) {
    size_t idx = ((size_t)blockIdx.x * 256 + threadIdx.x) * 4;
    int c4 = (int)(idx & 63);
    float4 sc = *(const float4*)(ss + c4);
    float4 sh = *(const float4*)(ss + 64 + c4);
    float4 v  = *(const float4*)(y + idx);
    float4 r;
    r.x = fmaxf(fmaf(v.x, sc.x, sh.x), 0.f);
    r.y = fmaxf(fmaf(v.y, sc.y, sh.y), 0.f);
    r.z = fmaxf(fmaf(v.z, sc.z, sh.z), 0.f);
    r.w = fmaxf(fmaf(v.w, sc.w, sh.w), 0.f);
    *(float4*)(out + idx) = r;
}

// ---------------------------------------------------------------------------
// BN+ReLU on NCHW, IN-PLACE (stage 2).
// ---------------------------------------------------------------------------
__global__ __launch_bounds__(256) void k_bnrelu_nchw(float* __restrict__ y,
                                                     const float* __restrict__ ss) {
    int c = (blockIdx.x / 49) % COUT;
    float scale = ss[c], shift = ss[64 + c];
    size_t idx = ((size_t)blockIdx.x * 1024) + threadIdx.x * 4;
    float4 v = *(const float4*)(y + idx);
    float4 r;
    r.x = fmaxf(fmaf(v.x, scale, shift), 0.f);
    r.y = fmaxf(fmaf(v.y, scale, shift), 0.f);
    r.z = fmaxf(fmaf(v.z, scale, shift), 0.f);
    r.w = fmaxf(fmaf(v.w, scale, shift), 0.f);
    *(float4*)(y + idx) = r;
}

// ---------------------------------------------------------------------------
// Workspace (~28 MB): weights 216 KB | part 0.8 MB | ss 512 B |
// bufB(xT / y1 NHWC) 25.7 MB.
// ---------------------------------------------------------------------------
extern "C" void kernel_launch(void* const* d_in, const int* in_sizes, int n_in,
                              void* d_out, int out_size, void* d_ws, size_t ws_size,
                              hipStream_t stream) {
    const float* x       = (const float*)d_in[0];
    const float* w_off1  = (const float*)d_in[1];
    const float* b_off1  = (const float*)d_in[2];
    const float* w_conv1 = (const float*)d_in[3];
    const float* gamma1  = (const float*)d_in[4];
    const float* beta1   = (const float*)d_in[5];
    const float* w_off2  = (const float*)d_in[6];
    const float* b_off2  = (const float*)d_in[7];
    const float* w_conv2 = (const float*)d_in[8];
    const float* gamma2  = (const float*)d_in[9];
    const float* beta2   = (const float*)d_in[10];
    float* out = (float*)d_out;

    char*  wsb  = (char*)d_ws;
    short* Wtdh = (short*)wsb;                           // 73728
    short* Wtdl = (short*)(wsb + 73728);                 // 73728
    short* Wtoh = (short*)(wsb + 147456);                // 36864
    short* Wtol = (short*)(wsb + 184320);                // 36864
    float* part = (float*)(wsb + 221184);                // <=1605632
    float* ss   = (float*)(wsb + 1826816);               // 512
    float* bufB = (float*)(wsb + 1827328);               // xT/y1: 25690112

    const int tp_blocks = (BATCH * HW) / 64;             // 1568
    const int bn_blocks = (BATCH * COUT * HW) / 1024;    // 6272

    // ---- stage 1 ----
    k_prepw       <<<216, 256, 0, stream>>>(w_conv1, w_off1, Wtdh, Wtdl, Wtoh, Wtol);
    k_transpose   <<<tp_blocks, 256, 0, stream>>>(x, bufB);
    k_fused<true> <<<NBLK, 256, 0, stream>>>(bufB, Wtoh, Wtol, b_off1, Wtdh, Wtdl, out, part);
    k_stats2      <<<64, 256, 0, stream>>>(part, gamma1, beta1, ss);
    k_bnrelu_nhwc <<<bn_blocks, 256, 0, stream>>>(out, ss, bufB);   // y1 (NHWC)

    // ---- stage 2 ----
    k_prepw       <<<216, 256, 0, stream>>>(w_conv2, w_off2, Wtdh, Wtdl, Wtoh, Wtol);
    k_fused<false><<<NBLK, 256, 0, stream>>>(bufB, Wtoh, Wtol, b_off2, Wtdh, Wtdl, out, part);
    k_stats2      <<<64, 256, 0, stream>>>(part, gamma2, beta2, ss);
    k_bnrelu_nchw <<<bn_blocks, 256, 0, stream>>>(out, ss);         // in-place
}

// Round 5
// 301.142 us; speedup vs baseline: 1.1371x; 1.0156x over previous
//
#include <hip/hip_runtime.h>

#define H 224
#define W 224
#define HW (H*W)
#define BATCH 2
#define CIN 64
#define COUT 64
#define NOFF 18
#define K576 576          // K = 64 ch * 9 taps
#define OFFS 20           // off LDS stride (18 live, f4-aligned)
#define NBLK (BATCH*HW/64)          // 1568 tiles (8x8 pixels)
#define NB8  (NBLK/8)               // 196 blocks per XCD span
#define TC8  28                     // 224/8 tiles per image row/col
#define XROW 68                     // staged patch ch-stride (64 + 4 pad)
#define PRW 10                      // patch rows (8 + 2 halo)
#define PCW 10                      // patch cols
#define LDROW 72                    // epilogue staging stride
#define TPB  (BATCH*HW/64)          // transpose blocks = 1568

typedef __attribute__((ext_vector_type(8))) short bf16x8;
typedef __attribute__((ext_vector_type(4))) short s16x4;
typedef __attribute__((ext_vector_type(4))) float f32x4;

__device__ inline short f2bf(float f) {
    unsigned u = __float_as_uint(f);
    u += 0x7FFF + ((u >> 16) & 1);
    return (short)(u >> 16);
}
__device__ inline float bf2f(short h) {
    return __uint_as_float(((unsigned)(unsigned short)h) << 16);
}
__device__ inline void split_bf(float x, short& hi, short& lo) {
    hi = f2bf(x);
    lo = f2bf(x - bf2f(hi));
}
__device__ inline void split_bf4(float a, float b, float c, float d,
                                 s16x4& h4, s16x4& l4) {
    short h0, l0, h1, l1, h2, l2, h3, l3;
    split_bf(a, h0, l0); split_bf(b, h1, l1);
    split_bf(c, h2, l2); split_bf(d, h3, l3);
    h4 = (s16x4){h0, h1, h2, h3};
    l4 = (s16x4){l0, l1, l2, l3};
}
__device__ inline void split_bf8(float a0, float a1, float a2, float a3,
                                 float a4, float a5, float a6, float a7,
                                 bf16x8& hi, bf16x8& lo) {
    s16x4 h0, l0, h1, l1;
    split_bf4(a0, a1, a2, a3, h0, l0);
    split_bf4(a4, a5, a6, a7, h1, l1);
    hi = __builtin_shufflevector(h0, h1, 0, 1, 2, 3, 4, 5, 6, 7);
    lo = __builtin_shufflevector(l0, l1, 0, 1, 2, 3, 4, 5, 6, 7);
}
__device__ inline int swizzle_blk(int raw) {
    return (raw & 7) * NB8 + (raw >> 3);
}
__device__ __forceinline__ float f4get(float4 v, int k) {
    switch (k & 3) { case 0: return v.x; case 1: return v.y; case 2: return v.z; default: return v.w; }
}

// ---------------------------------------------------------------------------
// Combined front kernel: blocks [0,TPB) transpose x NCHW->NHWC; blocks
// [TPB, TPB+216) prep BOTH stages' weights (wave-contiguous fragment layout):
// Deform:  Wd[((chunk*9+kt)*4+nt)*512 + lane*8 + e]
//   n = nt*16 + (lane&15); c = chunk*32 + (lane>>4)*8 + e; tap = kt
// Offconv: Wo[((chunk*9+kt)*2+ntb)*512 + lane*8 + e]   (n>=18 rows zero)
// Merging removes 2 launches vs R1's 9 (zero numerical impact).
// ---------------------------------------------------------------------------
__global__ __launch_bounds__(256) void k_prep_all(const float* __restrict__ x,
                                                  float* __restrict__ xT,
                                                  const float* __restrict__ wconv1,
                                                  const float* __restrict__ woff1,
                                                  const float* __restrict__ wconv2,
                                                  const float* __restrict__ woff2,
                                                  short* __restrict__ Wtd1h,
                                                  short* __restrict__ Wtd1l,
                                                  short* __restrict__ Wto1h,
                                                  short* __restrict__ Wto1l,
                                                  short* __restrict__ Wtd2h,
                                                  short* __restrict__ Wtd2l,
                                                  short* __restrict__ Wto2h,
                                                  short* __restrict__ Wto2l) {
    __shared__ float Lt[64][65];
    if (blockIdx.x < TPB) {
        // ---- NCHW -> NHWC transpose (identical to R1 k_transpose) ----
        int blk = blockIdx.x, t = threadIdx.x;
        int px0 = blk * 64;
        int b   = px0 / HW;
        int ij0 = px0 - b * HW;
        int lane = t & 63, g = t >> 6;
#pragma unroll
        for (int r = 0; r < 16; ++r) {
            int c = r * 4 + g;
            Lt[c][lane] = x[(b * CIN + c) * HW + ij0 + lane];
        }
        __syncthreads();
#pragma unroll
        for (int r = 0; r < 16; ++r) {
            int px = r * 4 + g;
            xT[((size_t)(b * HW + ij0 + px)) * 64 + lane] = Lt[lane][px];
        }
        return;
    }
    // ---- weight prep, both stages ----
    int t = (blockIdx.x - TPB) * 256 + threadIdx.x;
    if (t < COUT * K576) {
        int e = t & 7, lane = (t >> 3) & 63, rest = t >> 9;
        int nt = rest & 3, kt9 = rest >> 2;
        int kt = kt9 % 9, chunk = kt9 / 9;
        int n = nt * 16 + (lane & 15);
        int c = chunk * 32 + (lane >> 4) * 8 + e;
        short h, l;
        split_bf(wconv1[n * K576 + c * 9 + kt], h, l);
        Wtd1h[t] = h; Wtd1l[t] = l;
        split_bf(wconv2[n * K576 + c * 9 + kt], h, l);
        Wtd2h[t] = h; Wtd2l[t] = l;
    }
    int t2 = t - COUT * K576;
    if (t2 >= 0 && t2 < 32 * K576) {
        int e = t2 & 7, lane = (t2 >> 3) & 63, rest = t2 >> 9;
        int ntb = rest & 1, kt9 = rest >> 1;
        int kt = kt9 % 9, chunk = kt9 / 9;
        int n = ntb * 16 + (lane & 15);
        int c = chunk * 32 + (lane >> 4) * 8 + e;
        short h, l;
        float v1 = (n < NOFF) ? woff1[n * K576 + c * 9 + kt] : 0.0f;
        split_bf(v1, h, l);
        Wto1h[t2] = h; Wto1l[t2] = l;
        float v2 = (n < NOFF) ? woff2[n * K576 + c * 9 + kt] : 0.0f;
        split_bf(v2, h, l);
        Wto2h[t2] = h; Wto2l[t2] = l;
    }
}

// ---------------------------------------------------------------------------
// FUSED, wave-autonomous — BYTE-IDENTICAL to the R1 kernel that passed at
// 305.8 us / absmax 0.0625. (R2/R3's BN fusion + f32x8 interp refactor both
// failed correctness ~2.9-3.4 despite on-paper equivalence; reverted until a
// disasm-verified re-attempt.) Block = 8x8 pixels, 4 waves; each wave owns 16
// pixels and all 64 outputs; MFMA A-fragments produced in-register.
// ---------------------------------------------------------------------------
template <bool OUT_NHWC>
__global__ __launch_bounds__(256, 4) void k_fused(const float* __restrict__ xT,
                                                  const short* __restrict__ Wtoh,
                                                  const short* __restrict__ Wtol,
                                                  const float* __restrict__ boff,
                                                  const short* __restrict__ Wtdh,
                                                  const short* __restrict__ Wtdl,
                                                  float* __restrict__ out,
                                                  float* __restrict__ part) {
    // LDS: Xs 27200 | offL 5120 = 32320 B. Ld (18432) + Sr (2048) reuse them.
    __shared__ __align__(16) char smem[PRW * PCW * XROW * 4 + 64 * OFFS * 4];
    float* Xs   = (float*)smem;
    float* offL = (float*)(smem + PRW * PCW * XROW * 4);

    const int t    = threadIdx.x;
    const int lane = t & 63;
    const int wv   = t >> 6;
    const int l15  = lane & 15;
    const int quad = lane >> 4;
    const int vb   = swizzle_blk(blockIdx.x);
    const int b    = vb / (TC8 * TC8);
    const int rem  = vb - b * (TC8 * TC8);
    const int i0   = (rem / TC8) * 8;
    const int j0   = (rem % TC8) * 8;
    const int lp   = wv * 16 + l15;          // this lane's pixel 0..63
    const int i    = i0 + (lp >> 3);
    const int j    = j0 + (lp & 7);

    const float* xb = xT + (size_t)(b * HW) * 64;

    // ---- stage 10x10x64ch patch (border-clamped), shared by both phases ----
#pragma unroll
    for (int k = 0; k < 7; ++k) {
        int idx = k * 256 + t;               // 1600 = 100 slots x 16 f4
        if (idx < PRW * PCW * 16) {
            int slot = idx >> 4, e = idx & 15;
            int sr = slot / PCW, sc = slot - sr * PCW;
            int rr = min(max(i0 - 1 + sr, 0), H - 1);
            int cc = min(max(j0 - 1 + sc, 0), W - 1);
            *(float4*)&Xs[slot * XROW + e * 4] =
                *(const float4*)(xb + (size_t)(rr * W + cc) * 64 + e * 4);
        }
    }
    __syncthreads();

    // ============ PHASE 1: offset conv (zero-pad via mask), per-wave ============
    f32x4 aoc0 = (f32x4){0.f, 0.f, 0.f, 0.f};
    f32x4 aoc1 = (f32x4){0.f, 0.f, 0.f, 0.f};
#pragma unroll
    for (int kt = 0; kt < 9; ++kt) {
        const int di = kt / 3, dj = kt % 3;
        const int ii = i + di - 1, jj = j + dj - 1;
        const bool ok = (ii >= 0) && (ii < H) && (jj >= 0) && (jj < W);
        const float* xp = &Xs[(((lp >> 3) + di) * PCW + (lp & 7) + dj) * XROW + quad * 8];
#pragma unroll
        for (int chunk = 0; chunk < 2; ++chunk) {
            float4 va = make_float4(0.f, 0.f, 0.f, 0.f), vb4 = va;
            if (ok) {
                va  = *(const float4*)(xp + chunk * 32);
                vb4 = *(const float4*)(xp + chunk * 32 + 4);
            }
            bf16x8 afh, afl;
            split_bf8(va.x, va.y, va.z, va.w, vb4.x, vb4.y, vb4.z, vb4.w, afh, afl);
            const int fb = (chunk * 9 + kt) * 2 * 512 + lane * 8;
            bf16x8 bh0 = *(const bf16x8*)(Wtoh + fb);
            bf16x8 bl0 = *(const bf16x8*)(Wtol + fb);
            aoc0 = __builtin_amdgcn_mfma_f32_16x16x32_bf16(afh, bh0, aoc0, 0, 0, 0);
            aoc0 = __builtin_amdgcn_mfma_f32_16x16x32_bf16(afl, bh0, aoc0, 0, 0, 0);
            aoc0 = __builtin_amdgcn_mfma_f32_16x16x32_bf16(afh, bl0, aoc0, 0, 0, 0);
            bf16x8 bh1 = *(const bf16x8*)(Wtoh + fb + 512);
            bf16x8 bl1 = *(const bf16x8*)(Wtol + fb + 512);
            aoc1 = __builtin_amdgcn_mfma_f32_16x16x32_bf16(afh, bh1, aoc1, 0, 0, 0);
            aoc1 = __builtin_amdgcn_mfma_f32_16x16x32_bf16(afl, bh1, aoc1, 0, 0, 0);
            aoc1 = __builtin_amdgcn_mfma_f32_16x16x32_bf16(afh, bl1, aoc1, 0, 0, 0);
        }
    }
    // redistribute offsets: C layout holds [px=quad*4+r][n=l15(+16)] -> offL
    {
        const int pr0 = wv * 16 + quad * 4;
        const float bi = boff[l15];
#pragma unroll
        for (int r = 0; r < 4; ++r)
            offL[(pr0 + r) * OFFS + l15] = aoc0[r] + bi;
        if (l15 < 2) {
            const float bi2 = boff[16 + l15];
#pragma unroll
            for (int r = 0; r < 4; ++r)
                offL[(pr0 + r) * OFFS + 16 + l15] = aoc1[r] + bi2;
        }
    }
    __syncthreads();

    // ============ PHASE 2: deformable sampling + conv, per-wave ============
    const float* ofp = &offL[(wv * 16 + l15) * OFFS];
    const float4 ofA = *(const float4*)(ofp + 0);
    const float4 ofB = *(const float4*)(ofp + 4);
    const float4 ofC = *(const float4*)(ofp + 8);
    const float4 ofD = *(const float4*)(ofp + 12);
    const float4 ofE = *(const float4*)(ofp + 16);
#define OFFSEL(idx) ((idx) < 4 ? f4get(ofA, (idx)) : (idx) < 8 ? f4get(ofB, (idx)-4) : \
                     (idx) < 12 ? f4get(ofC, (idx)-8) : (idx) < 16 ? f4get(ofD, (idx)-12) : f4get(ofE, (idx)-16))

    f32x4 acc[4];
    acc[0] = (f32x4){0.f, 0.f, 0.f, 0.f};
    acc[1] = acc[0]; acc[2] = acc[0]; acc[3] = acc[0];

#pragma unroll
    for (int kt = 0; kt < 9; ++kt) {
        float px_f = (float)(i + kt / 3) + OFFSEL(kt);
        float py_f = (float)(j + kt % 3) + OFFSEL(9 + kt);
        float qx = floorf(px_f), qy = floorf(py_f);
        int ltx = min(max((int)qx, 0), H - 1);
        int lty = min(max((int)qy, 0), W - 1);
        int rbx = min(max((int)qx + 1, 0), H - 1);
        int rby = min(max((int)qy + 1, 0), W - 1);
        float cpx = fminf(fmaxf(px_f, 0.0f), (float)(H - 1));
        float cpy = fminf(fmaxf(py_f, 0.0f), (float)(W - 1));
        float alt = 1.0f + ((float)ltx - cpx);
        float arb = 1.0f - ((float)rbx - cpx);
        float blt = 1.0f + ((float)lty - cpy);
        float brb = 1.0f - ((float)rby - cpy);
        float g0 = alt * blt, g1 = arb * brb, g2 = alt * brb, g3 = arb * blt;
        int slr = ltx - (i0 - 1), srr = rbx - (i0 - 1);
        int slc = lty - (j0 - 1), src = rby - (j0 - 1);
        const bool inp = ((unsigned)slr < (unsigned)PRW) & ((unsigned)srr < (unsigned)PRW) &
                         ((unsigned)slc < (unsigned)PCW) & ((unsigned)src < (unsigned)PCW);
#pragma unroll
        for (int chunk = 0; chunk < 2; ++chunk) {
            const int ch = chunk * 32 + quad * 8;
            float s[8];
#pragma unroll
            for (int hf = 0; hf < 2; ++hf) {
                const int cho = ch + hf * 4;
                float4 v0, v1, v2, v3;
                if (inp) {
                    v0 = *(const float4*)&Xs[(slr * PCW + slc) * XROW + cho];
                    v1 = *(const float4*)&Xs[(srr * PCW + src) * XROW + cho];
                    v2 = *(const float4*)&Xs[(slr * PCW + src) * XROW + cho];
                    v3 = *(const float4*)&Xs[(srr * PCW + slc) * XROW + cho];
                } else {
                    v0 = *(const float4*)(xb + (size_t)(ltx * W + lty) * 64 + cho);
                    v1 = *(const float4*)(xb + (size_t)(rbx * W + rby) * 64 + cho);
                    v2 = *(const float4*)(xb + (size_t)(ltx * W + rby) * 64 + cho);
                    v3 = *(const float4*)(xb + (size_t)(rbx * W + lty) * 64 + cho);
                }
                s[hf * 4 + 0] = g0 * v0.x + g1 * v1.x + g2 * v2.x + g3 * v3.x;
                s[hf * 4 + 1] = g0 * v0.y + g1 * v1.y + g2 * v2.y + g3 * v3.y;
                s[hf * 4 + 2] = g0 * v0.z + g1 * v1.z + g2 * v2.z + g3 * v3.z;
                s[hf * 4 + 3] = g0 * v0.w + g1 * v1.w + g2 * v2.w + g3 * v3.w;
            }
            bf16x8 afh, afl;
            split_bf8(s[0], s[1], s[2], s[3], s[4], s[5], s[6], s[7], afh, afl);
#pragma unroll
            for (int nt = 0; nt < 4; ++nt) {
                const int fb = ((chunk * 9 + kt) * 4 + nt) * 512 + lane * 8;
                bf16x8 bfh = *(const bf16x8*)(Wtdh + fb);
                bf16x8 bfl = *(const bf16x8*)(Wtdl + fb);
                acc[nt] = __builtin_amdgcn_mfma_f32_16x16x32_bf16(afh, bfh, acc[nt], 0, 0, 0);
                acc[nt] = __builtin_amdgcn_mfma_f32_16x16x32_bf16(afl, bfh, acc[nt], 0, 0, 0);
                acc[nt] = __builtin_amdgcn_mfma_f32_16x16x32_bf16(afh, bfl, acc[nt], 0, 0, 0);
            }
        }
    }
#undef OFFSEL

    // ============ EPILOGUE: store + fused stats (Ld reuses Xs) ============
    __syncthreads();                          // all Xs reads done before overwrite
    float* Ld = Xs;
    const int pr0 = wv * 16 + quad * 4;
    if (OUT_NHWC) {
#pragma unroll
        for (int nt = 0; nt < 4; ++nt) {
            int c = nt * 16 + l15;
#pragma unroll
            for (int r = 0; r < 4; ++r)
                Ld[(pr0 + r) * LDROW + c] = acc[nt][r];
        }
        __syncthreads();
#pragma unroll
        for (int it = 0; it < 4; ++it) {      // 1024 f4 = 64px x 16 groups
            int idx = it * 256 + t;
            int px = idx >> 4, c4 = idx & 15;
            float4 v = *(float4*)&Ld[px * LDROW + c4 * 4];
            int pij = (i0 + (px >> 3)) * W + j0 + (px & 7);
            *(float4*)(out + (size_t)(b * HW + pij) * 64 + c4 * 4) = v;
        }
    } else {
#pragma unroll
        for (int nt = 0; nt < 4; ++nt) {
            int c = nt * 16 + l15;
#pragma unroll
            for (int r = 0; r < 4; ++r)
                Ld[c * LDROW + pr0 + r] = acc[nt][r];
        }
        __syncthreads();
#pragma unroll
        for (int it = 0; it < 4; ++it) {      // 1024 f4 = 64ch x 16 groups
            int idx = it * 256 + t;
            int c = idx >> 4, p4 = idx & 15;
            float4 v = *(float4*)&Ld[c * LDROW + p4 * 4];
            int pij = (i0 + (p4 >> 1)) * W + j0 + (p4 & 1) * 4;
            *(float4*)(out + (size_t)(b * COUT + c) * HW + pij) = v;
        }
    }
    {
        float* Sr = offL;                     // offsets dead; 2KB needed
        int c = t & 63, g = t >> 6;
        float s = 0.f, q = 0.f;
        if (OUT_NHWC) {
#pragma unroll
            for (int k = 0; k < 16; ++k) {
                float v = Ld[(g * 16 + k) * LDROW + c];
                s += v; q += v * v;
            }
        } else {
#pragma unroll
            for (int k4 = 0; k4 < 4; ++k4) {
                float4 v = *(const float4*)&Ld[c * LDROW + g * 16 + k4 * 4];
                s += v.x + v.y + v.z + v.w;
                q += v.x * v.x + v.y * v.y + v.z * v.z + v.w * v.w;
            }
        }
        Sr[g * 64 + c]       = s;
        Sr[256 + g * 64 + c] = q;
        __syncthreads();
        if (t < 64) {
            float ts = Sr[t] + Sr[64 + t] + Sr[128 + t] + Sr[192 + t];
            float tq = Sr[256 + t] + Sr[320 + t] + Sr[384 + t] + Sr[448 + t];
            part[(size_t)blockIdx.x * 128 + t]      = ts;
            part[(size_t)blockIdx.x * 128 + 64 + t] = tq;
        }
    }
}

// ---------------------------------------------------------------------------
// Reduce per-block partials -> per-channel scale/shift. grid = 64.
// ---------------------------------------------------------------------------
__global__ __launch_bounds__(256) void k_stats2(const float* __restrict__ part,
                                                const float* __restrict__ gamma,
                                                const float* __restrict__ beta,
                                                float* __restrict__ ss) {
    int c = blockIdx.x, t = threadIdx.x;
    float s = 0.f, q = 0.f;
    for (int k = t; k < NBLK; k += 256) {
        s += part[(size_t)k * 128 + c];
        q += part[(size_t)k * 128 + 64 + c];
    }
#pragma unroll
    for (int d = 32; d > 0; d >>= 1) {
        s += __shfl_down(s, d, 64);
        q += __shfl_down(q, d, 64);
    }
    __shared__ float red[8];
    int wv = t >> 6;
    if ((t & 63) == 0) { red[wv] = s; red[4 + wv] = q; }
    __syncthreads();
    if (t == 0) {
        float ts = red[0] + red[1] + red[2] + red[3];
        float tq = red[4] + red[5] + red[6] + red[7];
        const float inv_m = 1.0f / (float)(BATCH * HW);
        float mu    = ts * inv_m;
        float var   = tq * inv_m - mu * mu;
        float scale = rsqrtf(var + 1e-5f) * gamma[c];
        ss[c]      = scale;
        ss[64 + c] = beta[c] - mu * scale;
    }
}

// ---------------------------------------------------------------------------
// BN+ReLU on NHWC (stage 1).
// ---------------------------------------------------------------------------
__global__ __launch_bounds__(256) void k_bnrelu_nhwc(const float* __restrict__ y,
                                                     const float* __restrict__ ss,
                                                     float* __restrict__ out) {
    size_t idx = ((size_t)blockIdx.x * 256 + threadIdx.x) * 4;
    int c4 = (int)(idx & 63);
    float4 sc = *(const float4*)(ss + c4);
    float4 sh = *(const float4*)(ss + 64 + c4);
    float4 v  = *(const float4*)(y + idx);
    float4 r;
    r.x = fmaxf(fmaf(v.x, sc.x, sh.x), 0.f);
    r.y = fmaxf(fmaf(v.y, sc.y, sh.y), 0.f);
    r.z = fmaxf(fmaf(v.z, sc.z, sh.z), 0.f);
    r.w = fmaxf(fmaf(v.w, sc.w, sh.w), 0.f);
    *(float4*)(out + idx) = r;
}

// ---------------------------------------------------------------------------
// BN+ReLU on NCHW, IN-PLACE (stage 2).
// ---------------------------------------------------------------------------
__global__ __launch_bounds__(256) void k_bnrelu_nchw(float* __restrict__ y,
                                                     const float* __restrict__ ss) {
    int c = (blockIdx.x / 49) % COUT;
    float scale = ss[c], shift = ss[64 + c];
    size_t idx = ((size_t)blockIdx.x * 1024) + threadIdx.x * 4;
    float4 v = *(const float4*)(y + idx);
    float4 r;
    r.x = fmaxf(fmaf(v.x, scale, shift), 0.f);
    r.y = fmaxf(fmaf(v.y, scale, shift), 0.f);
    r.z = fmaxf(fmaf(v.z, scale, shift), 0.f);
    r.w = fmaxf(fmaf(v.w, scale, shift), 0.f);
    *(float4*)(y + idx) = r;
}

// ---------------------------------------------------------------------------
// Workspace (~27 MB): weights(2 stages) 432 KB | part 0.8 MB | ss 512 B |
// bufB(xT / y1 NHWC) 25.7 MB.  7 launches (was 9): prep+transpose merged,
// both stages' weights prepped up front.
// ---------------------------------------------------------------------------
extern "C" void kernel_launch(void* const* d_in, const int* in_sizes, int n_in,
                              void* d_out, int out_size, void* d_ws, size_t ws_size,
                              hipStream_t stream) {
    const float* x       = (const float*)d_in[0];
    const float* w_off1  = (const float*)d_in[1];
    const float* b_off1  = (const float*)d_in[2];
    const float* w_conv1 = (const float*)d_in[3];
    const float* gamma1  = (const float*)d_in[4];
    const float* beta1   = (const float*)d_in[5];
    const float* w_off2  = (const float*)d_in[6];
    const float* b_off2  = (const float*)d_in[7];
    const float* w_conv2 = (const float*)d_in[8];
    const float* gamma2  = (const float*)d_in[9];
    const float* beta2   = (const float*)d_in[10];
    float* out = (float*)d_out;

    char*  wsb   = (char*)d_ws;
    short* Wtd1h = (short*)wsb;                          // 73728
    short* Wtd1l = (short*)(wsb + 73728);                // 73728
    short* Wto1h = (short*)(wsb + 147456);               // 36864
    short* Wto1l = (short*)(wsb + 184320);               // 36864
    short* Wtd2h = (short*)(wsb + 221184);               // 73728
    short* Wtd2l = (short*)(wsb + 294912);               // 73728
    short* Wto2h = (short*)(wsb + 368640);               // 36864
    short* Wto2l = (short*)(wsb + 405504);               // 36864
    float* part  = (float*)(wsb + 442368);               // 802816
    float* ss    = (float*)(wsb + 1245184);              // 512
    float* bufB  = (float*)(wsb + 1245696);              // xT/y1: 25690112

    const int bn_blocks = (BATCH * COUT * HW) / 1024;    // 6272

    // ---- front: transpose + both weight preps in ONE launch ----
    k_prep_all    <<<TPB + 216, 256, 0, stream>>>(x, bufB, w_conv1, w_off1,
                                                  w_conv2, w_off2,
                                                  Wtd1h, Wtd1l, Wto1h, Wto1l,
                                                  Wtd2h, Wtd2l, Wto2h, Wto2l);

    // ---- stage 1 ----
    k_fused<true> <<<NBLK, 256, 0, stream>>>(bufB, Wto1h, Wto1l, b_off1,
                                             Wtd1h, Wtd1l, out, part);
    k_stats2      <<<64, 256, 0, stream>>>(part, gamma1, beta1, ss);
    k_bnrelu_nhwc <<<bn_blocks, 256, 0, stream>>>(out, ss, bufB);   // y1 (NHWC)

    // ---- stage 2 ----
    k_fused<false><<<NBLK, 256, 0, stream>>>(bufB, Wto2h, Wto2l, b_off2,
                                             Wtd2h, Wtd2l, out, part);
    k_stats2      <<<64, 256, 0, stream>>>(part, gamma2, beta2, ss);
    k_bnrelu_nchw <<<bn_blocks, 256, 0, stream>>>(out, ss);         // in-place
}

// Round 6
// 289.118 us; speedup vs baseline: 1.1843x; 1.0416x over previous
//
#include <hip/hip_runtime.h>

#define H 224
#define W 224
#define HW (H*W)
#define BATCH 2
#define CIN 64
#define COUT 64
#define NOFF 18
#define K576 576          // K = 64 ch * 9 taps
#define OFFS 20           // off LDS stride (18 live, f4-aligned)
#define NBLK (BATCH*HW/64)          // 1568 tiles (8x8 pixels)
#define NB8  (NBLK/8)               // 196 blocks per XCD span
#define TC8  28                     // 224/8 tiles per image row/col
#define XROW 68                     // staged patch ch-stride (64 + 4 pad)
#define PRW 10                      // patch rows (8 + 2 halo)
#define PCW 10                      // patch cols
#define LDROW 72                    // epilogue staging stride
#define TPB  (BATCH*HW/64)          // transpose blocks = 1568

typedef __attribute__((ext_vector_type(8))) short bf16x8;
typedef __attribute__((ext_vector_type(4))) short s16x4;
typedef __attribute__((ext_vector_type(4))) float f32x4;

__device__ inline short f2bf(float f) {
    unsigned u = __float_as_uint(f);
    u += 0x7FFF + ((u >> 16) & 1);
    return (short)(u >> 16);
}
__device__ inline float bf2f(short h) {
    return __uint_as_float(((unsigned)(unsigned short)h) << 16);
}
__device__ inline void split_bf(float x, short& hi, short& lo) {
    hi = f2bf(x);
    lo = f2bf(x - bf2f(hi));
}
__device__ inline void split_bf4(float a, float b, float c, float d,
                                 s16x4& h4, s16x4& l4) {
    short h0, l0, h1, l1, h2, l2, h3, l3;
    split_bf(a, h0, l0); split_bf(b, h1, l1);
    split_bf(c, h2, l2); split_bf(d, h3, l3);
    h4 = (s16x4){h0, h1, h2, h3};
    l4 = (s16x4){l0, l1, l2, l3};
}
__device__ inline void split_bf8(float a0, float a1, float a2, float a3,
                                 float a4, float a5, float a6, float a7,
                                 bf16x8& hi, bf16x8& lo) {
    s16x4 h0, l0, h1, l1;
    split_bf4(a0, a1, a2, a3, h0, l0);
    split_bf4(a4, a5, a6, a7, h1, l1);
    hi = __builtin_shufflevector(h0, h1, 0, 1, 2, 3, 4, 5, 6, 7);
    lo = __builtin_shufflevector(l0, l1, 0, 1, 2, 3, 4, 5, 6, 7);
}
__device__ inline bf16x8 cvt8hi(const float* s) {
    return (bf16x8){f2bf(s[0]), f2bf(s[1]), f2bf(s[2]), f2bf(s[3]),
                    f2bf(s[4]), f2bf(s[5]), f2bf(s[6]), f2bf(s[7])};
}
__device__ inline int swizzle_blk(int raw) {
    return (raw & 7) * NB8 + (raw >> 3);
}
__device__ __forceinline__ float f4get(float4 v, int k) {
    switch (k & 3) { case 0: return v.x; case 1: return v.y; case 2: return v.z; default: return v.w; }
}

// ---------------------------------------------------------------------------
// Combined front kernel: blocks [0,TPB) transpose x NCHW->NHWC; blocks
// [TPB, TPB+216) prep BOTH stages' weights (wave-contiguous fragment layout):
// Deform:  Wd[((chunk*9+kt)*4+nt)*512 + lane*8 + e]
//   n = nt*16 + (lane&15); c = chunk*32 + (lane>>4)*8 + e; tap = kt
// Offconv: Wo[((chunk*9+kt)*2+ntb)*512 + lane*8 + e]   (n>=18 rows zero)
// ---------------------------------------------------------------------------
__global__ __launch_bounds__(256) void k_prep_all(const float* __restrict__ x,
                                                  float* __restrict__ xT,
                                                  const float* __restrict__ wconv1,
                                                  const float* __restrict__ woff1,
                                                  const float* __restrict__ wconv2,
                                                  const float* __restrict__ woff2,
                                                  short* __restrict__ Wtd1h,
                                                  short* __restrict__ Wtd1l,
                                                  short* __restrict__ Wto1h,
                                                  short* __restrict__ Wto1l,
                                                  short* __restrict__ Wtd2h,
                                                  short* __restrict__ Wtd2l,
                                                  short* __restrict__ Wto2h,
                                                  short* __restrict__ Wto2l) {
    __shared__ float Lt[64][65];
    if (blockIdx.x < TPB) {
        // ---- NCHW -> NHWC transpose (identical to R1 k_transpose) ----
        int blk = blockIdx.x, t = threadIdx.x;
        int px0 = blk * 64;
        int b   = px0 / HW;
        int ij0 = px0 - b * HW;
        int lane = t & 63, g = t >> 6;
#pragma unroll
        for (int r = 0; r < 16; ++r) {
            int c = r * 4 + g;
            Lt[c][lane] = x[(b * CIN + c) * HW + ij0 + lane];
        }
        __syncthreads();
#pragma unroll
        for (int r = 0; r < 16; ++r) {
            int px = r * 4 + g;
            xT[((size_t)(b * HW + ij0 + px)) * 64 + lane] = Lt[lane][px];
        }
        return;
    }
    // ---- weight prep, both stages ----
    int t = (blockIdx.x - TPB) * 256 + threadIdx.x;
    if (t < COUT * K576) {
        int e = t & 7, lane = (t >> 3) & 63, rest = t >> 9;
        int nt = rest & 3, kt9 = rest >> 2;
        int kt = kt9 % 9, chunk = kt9 / 9;
        int n = nt * 16 + (lane & 15);
        int c = chunk * 32 + (lane >> 4) * 8 + e;
        short h, l;
        split_bf(wconv1[n * K576 + c * 9 + kt], h, l);
        Wtd1h[t] = h; Wtd1l[t] = l;
        split_bf(wconv2[n * K576 + c * 9 + kt], h, l);
        Wtd2h[t] = h; Wtd2l[t] = l;
    }
    int t2 = t - COUT * K576;
    if (t2 >= 0 && t2 < 32 * K576) {
        int e = t2 & 7, lane = (t2 >> 3) & 63, rest = t2 >> 9;
        int ntb = rest & 1, kt9 = rest >> 1;
        int kt = kt9 % 9, chunk = kt9 / 9;
        int n = ntb * 16 + (lane & 15);
        int c = chunk * 32 + (lane >> 4) * 8 + e;
        short h, l;
        float v1 = (n < NOFF) ? woff1[n * K576 + c * 9 + kt] : 0.0f;
        split_bf(v1, h, l);
        Wto1h[t2] = h; Wto1l[t2] = l;
        float v2 = (n < NOFF) ? woff2[n * K576 + c * 9 + kt] : 0.0f;
        split_bf(v2, h, l);
        Wto2h[t2] = h; Wto2l[t2] = l;
    }
}

// ---------------------------------------------------------------------------
// FUSED, wave-autonomous (R1 structure). Template LO controls deform-conv
// precision:
//   LO=true  (stage 1): full 3-term hi/lo bf16 product. REQUIRED — y1 feeds
//     stage-2's offset conv -> floor(); clamp-edge weights are discontinuous,
//     ~1e-3 offset error flips floors -> O(1) output error (R2 post-mortem).
//   LO=false (stage 2): hi*hi only. Deform-2 output feeds only BN+ReLU ->
//     final; cross-term error ~0.01-0.06 pre-BN << 0.795 threshold.
//     Cuts phase-2 MFMAs 216->72/lane, skips lo-split + Wtdl loads.
// Offset-conv phase is ALWAYS full 3-term (feeds floor in same kernel).
// ---------------------------------------------------------------------------
template <bool OUT_NHWC, bool LO>
__global__ __launch_bounds__(256, 4) void k_fused(const float* __restrict__ xT,
                                                  const short* __restrict__ Wtoh,
                                                  const short* __restrict__ Wtol,
                                                  const float* __restrict__ boff,
                                                  const short* __restrict__ Wtdh,
                                                  const short* __restrict__ Wtdl,
                                                  float* __restrict__ out,
                                                  float* __restrict__ part) {
    // LDS: Xs 27200 | offL 5120 = 32320 B. Ld (18432) + Sr (2048) reuse them.
    __shared__ __align__(16) char smem[PRW * PCW * XROW * 4 + 64 * OFFS * 4];
    float* Xs   = (float*)smem;
    float* offL = (float*)(smem + PRW * PCW * XROW * 4);

    const int t    = threadIdx.x;
    const int lane = t & 63;
    const int wv   = t >> 6;
    const int l15  = lane & 15;
    const int quad = lane >> 4;
    const int vb   = swizzle_blk(blockIdx.x);
    const int b    = vb / (TC8 * TC8);
    const int rem  = vb - b * (TC8 * TC8);
    const int i0   = (rem / TC8) * 8;
    const int j0   = (rem % TC8) * 8;
    const int lp   = wv * 16 + l15;          // this lane's pixel 0..63
    const int i    = i0 + (lp >> 3);
    const int j    = j0 + (lp & 7);

    const float* xb = xT + (size_t)(b * HW) * 64;

    // ---- stage 10x10x64ch patch (border-clamped), shared by both phases ----
#pragma unroll
    for (int k = 0; k < 7; ++k) {
        int idx = k * 256 + t;               // 1600 = 100 slots x 16 f4
        if (idx < PRW * PCW * 16) {
            int slot = idx >> 4, e = idx & 15;
            int sr = slot / PCW, sc = slot - sr * PCW;
            int rr = min(max(i0 - 1 + sr, 0), H - 1);
            int cc = min(max(j0 - 1 + sc, 0), W - 1);
            *(float4*)&Xs[slot * XROW + e * 4] =
                *(const float4*)(xb + (size_t)(rr * W + cc) * 64 + e * 4);
        }
    }
    __syncthreads();

    // ============ PHASE 1: offset conv (zero-pad via mask), per-wave ============
    f32x4 aoc0 = (f32x4){0.f, 0.f, 0.f, 0.f};
    f32x4 aoc1 = (f32x4){0.f, 0.f, 0.f, 0.f};
#pragma unroll
    for (int kt = 0; kt < 9; ++kt) {
        const int di = kt / 3, dj = kt % 3;
        const int ii = i + di - 1, jj = j + dj - 1;
        const bool ok = (ii >= 0) && (ii < H) && (jj >= 0) && (jj < W);
        const float* xp = &Xs[(((lp >> 3) + di) * PCW + (lp & 7) + dj) * XROW + quad * 8];
#pragma unroll
        for (int chunk = 0; chunk < 2; ++chunk) {
            float4 va = make_float4(0.f, 0.f, 0.f, 0.f), vb4 = va;
            if (ok) {
                va  = *(const float4*)(xp + chunk * 32);
                vb4 = *(const float4*)(xp + chunk * 32 + 4);
            }
            bf16x8 afh, afl;
            split_bf8(va.x, va.y, va.z, va.w, vb4.x, vb4.y, vb4.z, vb4.w, afh, afl);
            const int fb = (chunk * 9 + kt) * 2 * 512 + lane * 8;
            bf16x8 bh0 = *(const bf16x8*)(Wtoh + fb);
            bf16x8 bl0 = *(const bf16x8*)(Wtol + fb);
            aoc0 = __builtin_amdgcn_mfma_f32_16x16x32_bf16(afh, bh0, aoc0, 0, 0, 0);
            aoc0 = __builtin_amdgcn_mfma_f32_16x16x32_bf16(afl, bh0, aoc0, 0, 0, 0);
            aoc0 = __builtin_amdgcn_mfma_f32_16x16x32_bf16(afh, bl0, aoc0, 0, 0, 0);
            bf16x8 bh1 = *(const bf16x8*)(Wtoh + fb + 512);
            bf16x8 bl1 = *(const bf16x8*)(Wtol + fb + 512);
            aoc1 = __builtin_amdgcn_mfma_f32_16x16x32_bf16(afh, bh1, aoc1, 0, 0, 0);
            aoc1 = __builtin_amdgcn_mfma_f32_16x16x32_bf16(afl, bh1, aoc1, 0, 0, 0);
            aoc1 = __builtin_amdgcn_mfma_f32_16x16x32_bf16(afh, bl1, aoc1, 0, 0, 0);
        }
    }
    // redistribute offsets: C layout holds [px=quad*4+r][n=l15(+16)] -> offL
    {
        const int pr0 = wv * 16 + quad * 4;
        const float bi = boff[l15];
#pragma unroll
        for (int r = 0; r < 4; ++r)
            offL[(pr0 + r) * OFFS + l15] = aoc0[r] + bi;
        if (l15 < 2) {
            const float bi2 = boff[16 + l15];
#pragma unroll
            for (int r = 0; r < 4; ++r)
                offL[(pr0 + r) * OFFS + 16 + l15] = aoc1[r] + bi2;
        }
    }
    __syncthreads();

    // ============ PHASE 2: deformable sampling + conv, per-wave ============
    const float* ofp = &offL[(wv * 16 + l15) * OFFS];
    const float4 ofA = *(const float4*)(ofp + 0);
    const float4 ofB = *(const float4*)(ofp + 4);
    const float4 ofC = *(const float4*)(ofp + 8);
    const float4 ofD = *(const float4*)(ofp + 12);
    const float4 ofE = *(const float4*)(ofp + 16);
#define OFFSEL(idx) ((idx) < 4 ? f4get(ofA, (idx)) : (idx) < 8 ? f4get(ofB, (idx)-4) : \
                     (idx) < 12 ? f4get(ofC, (idx)-8) : (idx) < 16 ? f4get(ofD, (idx)-12) : f4get(ofE, (idx)-16))

    f32x4 acc[4];
    acc[0] = (f32x4){0.f, 0.f, 0.f, 0.f};
    acc[1] = acc[0]; acc[2] = acc[0]; acc[3] = acc[0];

#pragma unroll
    for (int kt = 0; kt < 9; ++kt) {
        float px_f = (float)(i + kt / 3) + OFFSEL(kt);
        float py_f = (float)(j + kt % 3) + OFFSEL(9 + kt);
        float qx = floorf(px_f), qy = floorf(py_f);
        int ltx = min(max((int)qx, 0), H - 1);
        int lty = min(max((int)qy, 0), W - 1);
        int rbx = min(max((int)qx + 1, 0), H - 1);
        int rby = min(max((int)qy + 1, 0), W - 1);
        float cpx = fminf(fmaxf(px_f, 0.0f), (float)(H - 1));
        float cpy = fminf(fmaxf(py_f, 0.0f), (float)(W - 1));
        float alt = 1.0f + ((float)ltx - cpx);
        float arb = 1.0f - ((float)rbx - cpx);
        float blt = 1.0f + ((float)lty - cpy);
        float brb = 1.0f - ((float)rby - cpy);
        float g0 = alt * blt, g1 = arb * brb, g2 = alt * brb, g3 = arb * blt;
        int slr = ltx - (i0 - 1), srr = rbx - (i0 - 1);
        int slc = lty - (j0 - 1), src = rby - (j0 - 1);
        const bool inp = ((unsigned)slr < (unsigned)PRW) & ((unsigned)srr < (unsigned)PRW) &
                         ((unsigned)slc < (unsigned)PCW) & ((unsigned)src < (unsigned)PCW);
#pragma unroll
        for (int chunk = 0; chunk < 2; ++chunk) {
            const int ch = chunk * 32 + quad * 8;
            float s[8];
#pragma unroll
            for (int hf = 0; hf < 2; ++hf) {
                const int cho = ch + hf * 4;
                float4 v0, v1, v2, v3;
                if (inp) {
                    v0 = *(const float4*)&Xs[(slr * PCW + slc) * XROW + cho];
                    v1 = *(const float4*)&Xs[(srr * PCW + src) * XROW + cho];
                    v2 = *(const float4*)&Xs[(slr * PCW + src) * XROW + cho];
                    v3 = *(const float4*)&Xs[(srr * PCW + slc) * XROW + cho];
                } else {
                    v0 = *(const float4*)(xb + (size_t)(ltx * W + lty) * 64 + cho);
                    v1 = *(const float4*)(xb + (size_t)(rbx * W + rby) * 64 + cho);
                    v2 = *(const float4*)(xb + (size_t)(ltx * W + rby) * 64 + cho);
                    v3 = *(const float4*)(xb + (size_t)(rbx * W + lty) * 64 + cho);
                }
                s[hf * 4 + 0] = g0 * v0.x + g1 * v1.x + g2 * v2.x + g3 * v3.x;
                s[hf * 4 + 1] = g0 * v0.y + g1 * v1.y + g2 * v2.y + g3 * v3.y;
                s[hf * 4 + 2] = g0 * v0.z + g1 * v1.z + g2 * v2.z + g3 * v3.z;
                s[hf * 4 + 3] = g0 * v0.w + g1 * v1.w + g2 * v2.w + g3 * v3.w;
            }
            if (LO) {
                bf16x8 afh, afl;
                split_bf8(s[0], s[1], s[2], s[3], s[4], s[5], s[6], s[7], afh, afl);
#pragma unroll
                for (int nt = 0; nt < 4; ++nt) {
                    const int fb = ((chunk * 9 + kt) * 4 + nt) * 512 + lane * 8;
                    bf16x8 bfh = *(const bf16x8*)(Wtdh + fb);
                    bf16x8 bfl = *(const bf16x8*)(Wtdl + fb);
                    acc[nt] = __builtin_amdgcn_mfma_f32_16x16x32_bf16(afh, bfh, acc[nt], 0, 0, 0);
                    acc[nt] = __builtin_amdgcn_mfma_f32_16x16x32_bf16(afl, bfh, acc[nt], 0, 0, 0);
                    acc[nt] = __builtin_amdgcn_mfma_f32_16x16x32_bf16(afh, bfl, acc[nt], 0, 0, 0);
                }
            } else {
                bf16x8 afh = cvt8hi(s);
#pragma unroll
                for (int nt = 0; nt < 4; ++nt) {
                    const int fb = ((chunk * 9 + kt) * 4 + nt) * 512 + lane * 8;
                    bf16x8 bfh = *(const bf16x8*)(Wtdh + fb);
                    acc[nt] = __builtin_amdgcn_mfma_f32_16x16x32_bf16(afh, bfh, acc[nt], 0, 0, 0);
                }
            }
        }
    }
#undef OFFSEL

    // ============ EPILOGUE: store + fused stats (Ld reuses Xs) ============
    __syncthreads();                          // all Xs reads done before overwrite
    float* Ld = Xs;
    const int pr0 = wv * 16 + quad * 4;
    if (OUT_NHWC) {
#pragma unroll
        for (int nt = 0; nt < 4; ++nt) {
            int c = nt * 16 + l15;
#pragma unroll
            for (int r = 0; r < 4; ++r)
                Ld[(pr0 + r) * LDROW + c] = acc[nt][r];
        }
        __syncthreads();
#pragma unroll
        for (int it = 0; it < 4; ++it) {      // 1024 f4 = 64px x 16 groups
            int idx = it * 256 + t;
            int px = idx >> 4, c4 = idx & 15;
            float4 v = *(float4*)&Ld[px * LDROW + c4 * 4];
            int pij = (i0 + (px >> 3)) * W + j0 + (px & 7);
            *(float4*)(out + (size_t)(b * HW + pij) * 64 + c4 * 4) = v;
        }
    } else {
#pragma unroll
        for (int nt = 0; nt < 4; ++nt) {
            int c = nt * 16 + l15;
#pragma unroll
            for (int r = 0; r < 4; ++r)
                Ld[c * LDROW + pr0 + r] = acc[nt][r];
        }
        __syncthreads();
#pragma unroll
        for (int it = 0; it < 4; ++it) {      // 1024 f4 = 64ch x 16 groups
            int idx = it * 256 + t;
            int c = idx >> 4, p4 = idx & 15;
            float4 v = *(float4*)&Ld[c * LDROW + p4 * 4];
            int pij = (i0 + (p4 >> 1)) * W + j0 + (p4 & 1) * 4;
            *(float4*)(out + (size_t)(b * COUT + c) * HW + pij) = v;
        }
    }
    {
        float* Sr = offL;                     // offsets dead; 2KB needed
        int c = t & 63, g = t >> 6;
        float s = 0.f, q = 0.f;
        if (OUT_NHWC) {
#pragma unroll
            for (int k = 0; k < 16; ++k) {
                float v = Ld[(g * 16 + k) * LDROW + c];
                s += v; q += v * v;
            }
        } else {
#pragma unroll
            for (int k4 = 0; k4 < 4; ++k4) {
                float4 v = *(const float4*)&Ld[c * LDROW + g * 16 + k4 * 4];
                s += v.x + v.y + v.z + v.w;
                q += v.x * v.x + v.y * v.y + v.z * v.z + v.w * v.w;
            }
        }
        Sr[g * 64 + c]       = s;
        Sr[256 + g * 64 + c] = q;
        __syncthreads();
        if (t < 64) {
            float ts = Sr[t] + Sr[64 + t] + Sr[128 + t] + Sr[192 + t];
            float tq = Sr[256 + t] + Sr[320 + t] + Sr[384 + t] + Sr[448 + t];
            part[(size_t)blockIdx.x * 128 + t]      = ts;
            part[(size_t)blockIdx.x * 128 + 64 + t] = tq;
        }
    }
}

// ---------------------------------------------------------------------------
// Reduce per-block partials -> per-channel scale/shift. grid = 64.
// ---------------------------------------------------------------------------
__global__ __launch_bounds__(256) void k_stats2(const float* __restrict__ part,
                                                const float* __restrict__ gamma,
                                                const float* __restrict__ beta,
                                                float* __restrict__ ss) {
    int c = blockIdx.x, t = threadIdx.x;
    float s = 0.f, q = 0.f;
    for (int k = t; k < NBLK; k += 256) {
        s += part[(size_t)k * 128 + c];
        q += part[(size_t)k * 128 + 64 + c];
    }
#pragma unroll
    for (int d = 32; d > 0; d >>= 1) {
        s += __shfl_down(s, d, 64);
        q += __shfl_down(q, d, 64);
    }
    __shared__ float red[8];
    int wv = t >> 6;
    if ((t & 63) == 0) { red[wv] = s; red[4 + wv] = q; }
    __syncthreads();
    if (t == 0) {
        float ts = red[0] + red[1] + red[2] + red[3];
        float tq = red[4] + red[5] + red[6] + red[7];
        const float inv_m = 1.0f / (float)(BATCH * HW);
        float mu    = ts * inv_m;
        float var   = tq * inv_m - mu * mu;
        float scale = rsqrtf(var + 1e-5f) * gamma[c];
        ss[c]      = scale;
        ss[64 + c] = beta[c] - mu * scale;
    }
}

// ---------------------------------------------------------------------------
// BN+ReLU on NHWC (stage 1).
// ---------------------------------------------------------------------------
__global__ __launch_bounds__(256) void k_bnrelu_nhwc(const float* __restrict__ y,
                                                     const float* __restrict__ ss,
                                                     float* __restrict__ out) {
    size_t idx = ((size_t)blockIdx.x * 256 + threadIdx.x) * 4;
    int c4 = (int)(idx & 63);
    float4 sc = *(const float4*)(ss + c4);
    float4 sh = *(const float4*)(ss + 64 + c4);
    float4 v  = *(const float4*)(y + idx);
    float4 r;
    r.x = fmaxf(fmaf(v.x, sc.x, sh.x), 0.f);
    r.y = fmaxf(fmaf(v.y, sc.y, sh.y), 0.f);
    r.z = fmaxf(fmaf(v.z, sc.z, sh.z), 0.f);
    r.w = fmaxf(fmaf(v.w, sc.w, sh.w), 0.f);
    *(float4*)(out + idx) = r;
}

// ---------------------------------------------------------------------------
// BN+ReLU on NCHW, IN-PLACE (stage 2).
// ---------------------------------------------------------------------------
__global__ __launch_bounds__(256) void k_bnrelu_nchw(float* __restrict__ y,
                                                     const float* __restrict__ ss) {
    int c = (blockIdx.x / 49) % COUT;
    float scale = ss[c], shift = ss[64 + c];
    size_t idx = ((size_t)blockIdx.x * 1024) + threadIdx.x * 4;
    float4 v = *(const float4*)(y + idx);
    float4 r;
    r.x = fmaxf(fmaf(v.x, scale, shift), 0.f);
    r.y = fmaxf(fmaf(v.y, scale, shift), 0.f);
    r.z = fmaxf(fmaf(v.z, scale, shift), 0.f);
    r.w = fmaxf(fmaf(v.w, scale, shift), 0.f);
    *(float4*)(y + idx) = r;
}

// ---------------------------------------------------------------------------
// Workspace (~27 MB): weights(2 stages) 432 KB | part 0.8 MB | ss 512 B |
// bufB(xT / y1 NHWC) 25.7 MB.  7 launches.
// ---------------------------------------------------------------------------
extern "C" void kernel_launch(void* const* d_in, const int* in_sizes, int n_in,
                              void* d_out, int out_size, void* d_ws, size_t ws_size,
                              hipStream_t stream) {
    const float* x       = (const float*)d_in[0];
    const float* w_off1  = (const float*)d_in[1];
    const float* b_off1  = (const float*)d_in[2];
    const float* w_conv1 = (const float*)d_in[3];
    const float* gamma1  = (const float*)d_in[4];
    const float* beta1   = (const float*)d_in[5];
    const float* w_off2  = (const float*)d_in[6];
    const float* b_off2  = (const float*)d_in[7];
    const float* w_conv2 = (const float*)d_in[8];
    const float* gamma2  = (const float*)d_in[9];
    const float* beta2   = (const float*)d_in[10];
    float* out = (float*)d_out;

    char*  wsb   = (char*)d_ws;
    short* Wtd1h = (short*)wsb;                          // 73728
    short* Wtd1l = (short*)(wsb + 73728);                // 73728
    short* Wto1h = (short*)(wsb + 147456);               // 36864
    short* Wto1l = (short*)(wsb + 184320);               // 36864
    short* Wtd2h = (short*)(wsb + 221184);               // 73728
    short* Wtd2l = (short*)(wsb + 294912);               // 73728
    short* Wto2h = (short*)(wsb + 368640);               // 36864
    short* Wto2l = (short*)(wsb + 405504);               // 36864
    float* part  = (float*)(wsb + 442368);               // 802816
    float* ss    = (float*)(wsb + 1245184);              // 512
    float* bufB  = (float*)(wsb + 1245696);              // xT/y1: 25690112

    const int bn_blocks = (BATCH * COUT * HW) / 1024;    // 6272

    // ---- front: transpose + both weight preps in ONE launch ----
    k_prep_all    <<<TPB + 216, 256, 0, stream>>>(x, bufB, w_conv1, w_off1,
                                                  w_conv2, w_off2,
                                                  Wtd1h, Wtd1l, Wto1h, Wto1l,
                                                  Wtd2h, Wtd2l, Wto2h, Wto2l);

    // ---- stage 1 (full hi/lo deform conv: y1 feeds stage-2 floors) ----
    k_fused<true, true> <<<NBLK, 256, 0, stream>>>(bufB, Wto1h, Wto1l, b_off1,
                                                   Wtd1h, Wtd1l, out, part);
    k_stats2      <<<64, 256, 0, stream>>>(part, gamma1, beta1, ss);
    k_bnrelu_nhwc <<<bn_blocks, 256, 0, stream>>>(out, ss, bufB);   // y1 (NHWC)

    // ---- stage 2 (hi-only deform conv: output only feeds BN+ReLU) ----
    k_fused<false, false><<<NBLK, 256, 0, stream>>>(bufB, Wto2h, Wto2l, b_off2,
                                                    Wtd2h, Wtd2l, out, part);
    k_stats2      <<<64, 256, 0, stream>>>(part, gamma2, beta2, ss);
    k_bnrelu_nchw <<<bn_blocks, 256, 0, stream>>>(out, ss);         // in-place
}